// Round 2
// baseline (409.889 us; speedup 1.0000x reference)
//
#include <hip/hip_runtime.h>

#define S_LEN 1024
#define DH 64
#define NBH 32
#define CROWS 1920                   // 1024+512+256+128 coarse rows
#define HEAD_K (CROWS * DH)          // 122880 elements per head
#define NCHUNK (HEAD_K / 8)          // 15360 16-byte fragment chunks per head
#define ATTN_OFF (NBH * S_LEN * DH)  // start of combined_attention in d_out
#define PSTR 1928                    // LDS probs row stride (bf16 elems, padded)
#define QWSTR 72                     // qW LDS row stride (ushorts; 144B = 16B-aligned rows)

typedef __attribute__((ext_vector_type(8))) short bf8_t;
typedef __attribute__((ext_vector_type(4))) float f32x4_t;

__device__ __forceinline__ unsigned short f2bf(float x) {
  unsigned u = __float_as_uint(x);
  u += 0x7fffu + ((u >> 16) & 1u);
  return (unsigned short)(u >> 16);
}
__device__ __forceinline__ float bf2f(unsigned short h) {
  return __uint_as_float(((unsigned)h) << 16);
}

// ---------------------------------------------------------------------------
// PREP (lean): pool K -> pack B-frags (no projection: W is applied to Q in
// fused, bias cancels in softmax); pool V (+-2 halo) -> tridiagonal U^T U
// stencil -> pack mpvB. One barrier. LDS ~37 KB -> 4 blocks/CU, 960 blocks
// fully resident. Block bid==0 additionally packs W hi/lo bf16 B-frags.
// ---------------------------------------------------------------------------
__global__ __launch_bounds__(256, 4) void prep_kernel(
    const float* __restrict__ key, const float* __restrict__ value,
    const float* __restrict__ W,
    unsigned short* __restrict__ pkB, unsigned short* __restrict__ mpvB,
    unsigned short* __restrict__ WB)
{
  __shared__ __align__(16) float pkK[64 * 68];
  __shared__ __align__(16) float pkV[68 * 68];
  __shared__ float coefs[64 * 4];
  const int t = threadIdx.x;
  const int bid = blockIdx.x;
  const int bh = bid / 30;
  const int tt = bid % 30;
  int si, jt;
  if (tt < 16)      { si = 0; jt = tt; }
  else if (tt < 24) { si = 1; jt = tt - 16; }
  else if (tt < 28) { si = 2; jt = tt - 24; }
  else              { si = 3; jt = tt - 28; }
  const int s = 1 << si;
  const int L = 1024 >> si;
  const int off = (si == 0) ? 0 : (si == 1) ? 1024 : (si == 2) ? 1536 : 1792;
  const int j0 = jt << 6;
  const float invs = 1.0f / (float)s;

  // pool K rows j0..j0+63 (float4-vectorized)
  const float* Kp = key + bh * (S_LEN * DH);
  for (int i = t; i < 1024; i += 256) {
    const int j = i >> 4, d4 = (i & 15) << 2;
    const float* src = Kp + (j0 + j) * s * DH + d4;
    float4 a = {0.f, 0.f, 0.f, 0.f};
    for (int f = 0; f < s; f++) {
      const float4 kv = *(const float4*)(src + f * DH);
      a.x += kv.x; a.y += kv.y; a.z += kv.z; a.w += kv.w;
    }
    a.x *= invs; a.y *= invs; a.z *= invs; a.w *= invs;
    *(float4*)&pkK[j * 68 + d4] = a;
  }

  // pool V rows j0-2 .. j0+65 (clamped) into pkV[68 rows]
  const float* Vp = value + bh * (S_LEN * DH);
  for (int i = t; i < 1088; i += 256) {
    const int hj = i >> 4, d4 = (i & 15) << 2;
    const int jg = min(max(j0 - 2 + hj, 0), L - 1);
    const float* src = Vp + jg * s * DH + d4;
    float4 a = {0.f, 0.f, 0.f, 0.f};
    for (int f = 0; f < s; f++) {
      const float4 vv = *(const float4*)(src + f * DH);
      a.x += vv.x; a.y += vv.y; a.z += vv.z; a.w += vv.w;
    }
    a.x *= invs; a.y *= invs; a.z *= invs; a.w *= invs;
    *(float4*)&pkV[hj * 68 + d4] = a;
  }

  // tridiagonal stencil coefficients of M = U^T U for this block's 64 rows
  if (t < 64) {
    const int j = j0 + t;
    float cm = 0.f, cc = 0.f, cp = 0.f;
    const int klo = max(0, (j - 1) * s);
    const int khi = min(S_LEN - 1, (j + 2) * s);
    for (int kf = klo; kf <= khi; kf++) {
      float srcp = ((float)kf + 0.5f) * invs - 0.5f;
      srcp = fminf(fmaxf(srcp, 0.f), (float)(L - 1));
      const int i0 = (int)floorf(srcp);
      const int i1 = min(i0 + 1, L - 1);
      const float w = srcp - (float)i0;
      float u = 0.f;
      if (i0 == j) u += 1.f - w;
      if (i1 == j) u += w;
      if (u != 0.f) {
        const float g0 = u * (1.f - w), g1 = u * w;
        if (i0 == j) cc += g0; else cm += g0;
        if (i1 == j) cc += g1; else cp += g1;
      }
    }
    coefs[t * 4 + 0] = cm; coefs[t * 4 + 1] = cc; coefs[t * 4 + 2] = cp;
  }
  __syncthreads();

  // pack pooled-K B-frags: chunk[(kt*2+db)*64+ln][j] = pk[kt*16+(ln&15)][db*32+(ln>>4)*8+j]
  const int ktg0 = (off + j0) >> 4;
  for (int c = t; c < 512; c += 256) {
    const int ktl = c >> 7;
    const int db  = (c >> 6) & 1;
    const int ln  = c & 63;
    const int kl  = ktl * 16 + (ln & 15);
    const int e0p = db * 32 + ((ln >> 4) & 3) * 8;
    const float4 a  = *(const float4*)&pkK[kl * 68 + e0p];
    const float4 c4 = *(const float4*)&pkK[kl * 68 + e0p + 4];
    bf8_t v;
    v[0] = (short)f2bf(a.x);  v[1] = (short)f2bf(a.y);
    v[2] = (short)f2bf(a.z);  v[3] = (short)f2bf(a.w);
    v[4] = (short)f2bf(c4.x); v[5] = (short)f2bf(c4.y);
    v[6] = (short)f2bf(c4.z); v[7] = (short)f2bf(c4.w);
    ((bf8_t*)pkB)[bh * NCHUNK + ((ktg0 + ktl) * 2 + db) * 64 + ln] = v;
  }

  // Mpv = stencil(pooled V), packed in MFMA-B frag order
  const int kbg0 = (off + j0) >> 5;
  for (int c = t; c < 512; c += 256) {
    const int kbl = c >> 8;
    const int nt  = (c >> 6) & 3;
    const int ln  = c & 63;
    const int d   = nt * 16 + (ln & 15);
    const int r0  = kbl * 32 + ((ln >> 4) & 3) * 8;
    bf8_t v;
    #pragma unroll
    for (int jj = 0; jj < 8; jj++) {
      const int rl = r0 + jj;
      const float val = coefs[rl * 4 + 0] * pkV[(rl + 1) * 68 + d] +
                        coefs[rl * 4 + 1] * pkV[(rl + 2) * 68 + d] +
                        coefs[rl * 4 + 2] * pkV[(rl + 3) * 68 + d];
      v[jj] = (short)f2bf(val);
    }
    ((bf8_t*)mpvB)[bh * NCHUNK + ((kbg0 + kbl) * 4 + nt) * 64 + ln] = v;
  }

  // W hi/lo bf16 B-frags: chunk ((si*4+nt)*4 + (lo*2+kb))*64+ln,
  // elem j = W[si][e=kb*32+((ln>>4)&3)*8+j][d=nt*16+(ln&15)]
  if (bid == 0) {
    for (int c = t; c < 4096; c += 256) {
      const int ws = c >> 10;
      const int nt = (c >> 8) & 3;
      const int p  = (c >> 6) & 3;
      const int kb = p & 1;
      const int lo = p >> 1;
      const int ln = c & 63;
      const int d  = nt * 16 + (ln & 15);
      const int e0 = kb * 32 + ((ln >> 4) & 3) * 8;
      bf8_t v;
      #pragma unroll
      for (int j = 0; j < 8; j++) {
        const float wv = W[ws * 4096 + (e0 + j) * 64 + d];
        const unsigned short hi = f2bf(wv);
        v[j] = lo ? (short)f2bf(wv - bf2f(hi)) : (short)hi;
      }
      ((bf8_t*)WB)[c] = v;
    }
  }
}

// ---------------------------------------------------------------------------
// FUSED: 256 threads (round-0 structure), 2 blocks/CU.
// P0: qW_si = q @ W_si via split-bf16 MFMA (wave w owns scale w) -> LDS ->
//     per-scale A-frags. Bias dropped (cancels in softmax).
// P1: scores = qW . pk via MFMA, bf16 to LDS.
// P2: per-row per-scale max+exp (UNNORMALIZED), 1/sum -> sInv (2 passes).
// P3: segmented MFMA over scales, sInv folded in epilogue.
// P4: combined_attention, hoisted interp coefs, sInv folded.
// ---------------------------------------------------------------------------
__global__ __launch_bounds__(256, 2) void fused_attn_kernel(
    const float* __restrict__ query, const unsigned short* __restrict__ pkB,
    const unsigned short* __restrict__ mpvB,
    const unsigned short* __restrict__ WB, float* __restrict__ out)
{
  __shared__ __align__(16) unsigned short prbf[16 * PSTR];
  __shared__ __align__(16) unsigned short qwl[4][16 * QWSTR];
  __shared__ float sInv[16 * 4];
  const int t    = threadIdx.x;
  const int bh   = blockIdx.x & 31;
  const int qt   = blockIdx.x >> 5;
  const int q0   = qt << 4;
  const int wave = t >> 6;
  const int lane = t & 63;
  const int quad = lane >> 4;
  const int n16  = lane & 15;

  // zero pad columns (finite target for unclamped i0+1 lerp read in P4)
  if (t < 128) prbf[(t >> 3) * PSTR + 1920 + (t & 7)] = 0;

  // ---- P0: query A-frags (hi/lo split), qW via MFMA, stage per-scale A-frags
  bf8_t ah0, ah1, al0, al1;
  {
    const float* qrow = query + bh * (S_LEN * DH) + (q0 + n16) * DH;
    const float4 a0 = *(const float4*)(qrow + quad * 8);
    const float4 a1 = *(const float4*)(qrow + quad * 8 + 4);
    const float4 a2 = *(const float4*)(qrow + 32 + quad * 8);
    const float4 a3 = *(const float4*)(qrow + 32 + quad * 8 + 4);
    const float q0v[16] = {a0.x, a0.y, a0.z, a0.w, a1.x, a1.y, a1.z, a1.w,
                           a2.x, a2.y, a2.z, a2.w, a3.x, a3.y, a3.z, a3.w};
    #pragma unroll
    for (int j = 0; j < 8; j++) {
      const unsigned short h0 = f2bf(q0v[j]);
      const unsigned short h1 = f2bf(q0v[8 + j]);
      ah0[j] = (short)h0; al0[j] = (short)f2bf(q0v[j] - bf2f(h0));
      ah1[j] = (short)h1; al1[j] = (short)f2bf(q0v[8 + j] - bf2f(h1));
    }
  }
  {
    const bf8_t* WBf = (const bf8_t*)WB;
    const int si = wave;   // wave owns one scale
    #pragma unroll
    for (int nt = 0; nt < 4; nt++) {
      const int base = ((si * 4 + nt) * 4) * 64 + lane;
      const bf8_t wh0 = WBf[base];
      const bf8_t wh1 = WBf[base + 64];
      const bf8_t wl0 = WBf[base + 128];
      const bf8_t wl1 = WBf[base + 192];
      f32x4_t c = {0.f, 0.f, 0.f, 0.f};
      c = __builtin_amdgcn_mfma_f32_16x16x32_bf16(ah0, wh0, c, 0, 0, 0);
      c = __builtin_amdgcn_mfma_f32_16x16x32_bf16(ah1, wh1, c, 0, 0, 0);
      c = __builtin_amdgcn_mfma_f32_16x16x32_bf16(al0, wh0, c, 0, 0, 0);
      c = __builtin_amdgcn_mfma_f32_16x16x32_bf16(al1, wh1, c, 0, 0, 0);
      c = __builtin_amdgcn_mfma_f32_16x16x32_bf16(ah0, wl0, c, 0, 0, 0);
      c = __builtin_amdgcn_mfma_f32_16x16x32_bf16(ah1, wl1, c, 0, 0, 0);
      #pragma unroll
      for (int i = 0; i < 4; i++)
        qwl[si][(quad * 4 + i) * QWSTR + nt * 16 + n16] = f2bf(c[i]);
    }
  }
  __syncthreads();

  bf8_t af[4][2];
  #pragma unroll
  for (int si = 0; si < 4; si++) {
    af[si][0] = *(const bf8_t*)&qwl[si][n16 * QWSTR + quad * 8];
    af[si][1] = *(const bf8_t*)&qwl[si][n16 * QWSTR + quad * 8 + 32];
  }

  // ---- P1: scores via MFMA; bf16 (x 1/sqrt(D)) to LDS ----
  {
    const bf8_t* pB = (const bf8_t*)pkB + bh * NCHUNK;
    #pragma unroll
    for (int si = 0; si < 4; si++) {
      const int kt0 = (si == 0) ? 0 : (si == 1) ? 64 : (si == 2) ? 96 : 112;
      const int kt1 = (si == 0) ? 64 : (si == 1) ? 96 : (si == 2) ? 112 : 120;
      for (int kt = kt0 + wave; kt < kt1; kt += 4) {
        const bf8_t b0 = pB[(kt * 2 + 0) * 64 + lane];
        const bf8_t b1 = pB[(kt * 2 + 1) * 64 + lane];
        f32x4_t c = {0.f, 0.f, 0.f, 0.f};
        c = __builtin_amdgcn_mfma_f32_16x16x32_bf16(af[si][0], b0, c, 0, 0, 0);
        c = __builtin_amdgcn_mfma_f32_16x16x32_bf16(af[si][1], b1, c, 0, 0, 0);
        const int col = kt * 16 + n16;
        #pragma unroll
        for (int i = 0; i < 4; i++)
          prbf[(quad * 4 + i) * PSTR + col] = f2bf(c[i] * 0.125f);
      }
    }
  }
  __syncthreads();

  // ---- P2: per-row per-scale max + exp (UNNORMALIZED), 1/sum -> sInv ----
  {
    const int rr = t >> 4;
    const int g  = t & 15;
    unsigned short* prr = prbf + rr * PSTR;
    #pragma unroll
    for (int si = 0; si < 4; si++) {
      const int nch = (1024 >> si) >> 3;  // bf8 chunks
      const int off = (si == 0) ? 0 : (si == 1) ? 1024 : (si == 2) ? 1536 : 1792;
      bf8_t* base = (bf8_t*)(prr + off);
      float m = -1e30f;
      for (int ch = g; ch < nch; ch += 16) {
        const bf8_t u = base[ch];
        #pragma unroll
        for (int e = 0; e < 8; e++) m = fmaxf(m, bf2f((unsigned short)u[e]));
      }
      #pragma unroll
      for (int dlt = 8; dlt >= 1; dlt >>= 1) m = fmaxf(m, __shfl_xor(m, dlt));
      float ssum = 0.f;
      for (int ch = g; ch < nch; ch += 16) {
        bf8_t u = base[ch];
        #pragma unroll
        for (int e = 0; e < 8; e++) {
          const float ev = __expf(bf2f((unsigned short)u[e]) - m);
          ssum += ev;
          u[e] = (short)f2bf(ev);
        }
        base[ch] = u;
      }
      #pragma unroll
      for (int dlt = 8; dlt >= 1; dlt >>= 1) ssum += __shfl_xor(ssum, dlt);
      if (g == 0) sInv[rr * 4 + si] = 1.0f / ssum;
    }
  }
  __syncthreads();

  // ---- P3: out = 0.25 * sum_si inv_si * (e_si @ Mpv_si); wave owns d-tile ----
  {
    const bf8_t* pM = (const bf8_t*)mpvB + bh * NCHUNK;
    f32x4_t s0 = {0.f, 0.f, 0.f, 0.f}, s1 = s0, s2 = s0, s3 = s0;
    for (int kb = 0; kb < 32; kb++) {
      const bf8_t a  = *(const bf8_t*)(prbf + n16 * PSTR + kb * 32 + quad * 8);
      const bf8_t bb = pM[(kb * 4 + wave) * 64 + lane];
      s0 = __builtin_amdgcn_mfma_f32_16x16x32_bf16(a, bb, s0, 0, 0, 0);
    }
    for (int kb = 32; kb < 48; kb++) {
      const bf8_t a  = *(const bf8_t*)(prbf + n16 * PSTR + kb * 32 + quad * 8);
      const bf8_t bb = pM[(kb * 4 + wave) * 64 + lane];
      s1 = __builtin_amdgcn_mfma_f32_16x16x32_bf16(a, bb, s1, 0, 0, 0);
    }
    for (int kb = 48; kb < 56; kb++) {
      const bf8_t a  = *(const bf8_t*)(prbf + n16 * PSTR + kb * 32 + quad * 8);
      const bf8_t bb = pM[(kb * 4 + wave) * 64 + lane];
      s2 = __builtin_amdgcn_mfma_f32_16x16x32_bf16(a, bb, s2, 0, 0, 0);
    }
    for (int kb = 56; kb < 60; kb++) {
      const bf8_t a  = *(const bf8_t*)(prbf + n16 * PSTR + kb * 32 + quad * 8);
      const bf8_t bb = pM[(kb * 4 + wave) * 64 + lane];
      s3 = __builtin_amdgcn_mfma_f32_16x16x32_bf16(a, bb, s3, 0, 0, 0);
    }
    float* ob = out + bh * (S_LEN * DH) + q0 * DH;
    #pragma unroll
    for (int i = 0; i < 4; i++) {
      const int row = quad * 4 + i;
      ob[row * DH + wave * 16 + n16] =
          0.25f * (s0[i] * sInv[row * 4 + 0] + s1[i] * sInv[row * 4 + 1] +
                   s2[i] * sInv[row * 4 + 2] + s3[i] * sInv[row * 4 + 3]);
    }
  }

  // ---- P4: combined_attention; fixed columns/thread, hoisted interp coefs ----
  {
    float* ab = out + ATTN_OFF + (size_t)bh * (S_LEN * S_LEN) + (size_t)q0 * S_LEN;
    const int k0 = t << 2;              // thread owns columns k0..k0+3 for all rows
    int   iofs[3][4];
    float wgt[3][4];
    #pragma unroll
    for (int si = 1; si < 4; si++) {
      const int   L     = 1024 >> si;
      const int   off2  = (si == 1) ? 1024 : (si == 2) ? 1536 : 1792;
      const float inv_s = (si == 1) ? 0.5f : (si == 2) ? 0.25f : 0.125f;
      #pragma unroll
      for (int kk = 0; kk < 4; kk++) {
        float srcp = ((float)(k0 + kk) + 0.5f) * inv_s - 0.5f;
        srcp = fminf(fmaxf(srcp, 0.f), (float)(L - 1));
        const int i0 = (int)floorf(srcp);
        iofs[si - 1][kk] = off2 + i0;
        wgt[si - 1][kk]  = srcp - (float)i0;
      }
    }
    for (int rr = 0; rr < 16; rr++) {
      const unsigned short* p2 = prbf + rr * PSTR;
      const float iv0 = sInv[rr * 4 + 0];
      const float iv1 = sInv[rr * 4 + 1];
      const float iv2 = sInv[rr * 4 + 2];
      const float iv3 = sInv[rr * 4 + 3];
      const ushort4 bs = *(const ushort4*)(p2 + k0);
      float res[4] = {bf2f(bs.x) * iv0, bf2f(bs.y) * iv0,
                      bf2f(bs.z) * iv0, bf2f(bs.w) * iv0};
      #pragma unroll
      for (int si = 1; si < 4; si++) {
        const float ivs = (si == 1) ? iv1 : (si == 2) ? iv2 : iv3;
        #pragma unroll
        for (int kk = 0; kk < 4; kk++) {
          const int   io = iofs[si - 1][kk];
          const float w  = wgt[si - 1][kk];
          const float e0 = bf2f(p2[io]);
          const float e1 = bf2f(p2[io + 1]);
          res[kk] += ivs * (e0 + w * (e1 - e0));
        }
      }
      *(float4*)(ab + rr * 1024 + k0) =
          make_float4(res[0] * 0.25f, res[1] * 0.25f,
                      res[2] * 0.25f, res[3] * 0.25f);
    }
  }
}

// ---------------------------------------------------------------------------
extern "C" void kernel_launch(void* const* d_in, const int* in_sizes, int n_in,
                              void* d_out, int out_size, void* d_ws, size_t ws_size,
                              hipStream_t stream) {
  (void)in_sizes; (void)n_in; (void)out_size; (void)ws_size;
  const float* query = (const float*)d_in[0];
  const float* key   = (const float*)d_in[1];
  const float* value = (const float*)d_in[2];
  const float* W     = (const float*)d_in[3];
  float* out = (float*)d_out;

  unsigned short* pkB  = (unsigned short*)d_ws;                  // 7.9 MB bf16
  unsigned short* mpvB = pkB + (size_t)NBH * HEAD_K;             // 7.9 MB bf16
  unsigned short* WB   = mpvB + (size_t)NBH * HEAD_K;            // 64 KB bf16 (W hi/lo frags)

  prep_kernel<<<NBH * 30, 256, 0, stream>>>(key, value, W, pkB, mpvB, WB);
  fused_attn_kernel<<<NBH * 64, 256, 0, stream>>>(query, pkB, mpvB, WB, out);
}

// Round 3
// 310.539 us; speedup vs baseline: 1.3199x; 1.3199x over previous
//
#include <hip/hip_runtime.h>

#define S_LEN 1024
#define DH 64
#define NBH 32
#define CROWS 1920                   // 1024+512+256+128 coarse rows
#define HEAD_K (CROWS * DH)          // 122880 elements per head
#define NCHUNK (HEAD_K / 8)          // 15360 16-byte fragment chunks per head
#define ATTN_OFF (NBH * S_LEN * DH)  // start of combined_attention in d_out
#define PSTR 1928                    // LDS probs row stride (bf16 elems, padded)

typedef __attribute__((ext_vector_type(8))) short bf8_t;
typedef __attribute__((ext_vector_type(4))) float f32x4_t;

__device__ __forceinline__ unsigned short f2bf(float x) {
  unsigned u = __float_as_uint(x);
  u += 0x7fffu + ((u >> 16) & 1u);
  return (unsigned short)(u >> 16);
}
__device__ __forceinline__ float bf2f(unsigned short h) {
  return __uint_as_float(((unsigned)h) << 16);
}

// ---------------------------------------------------------------------------
// PREP (single kernel): pool K -> fp32 projection -> pack projB B-frags;
// pool V (+-2 halo) -> tridiagonal U^T U stencil -> pack mpvB B-frags.
// No pv global round-trip, no second prep launch.  LDS ~53 KB -> 3 blocks/CU.
// ---------------------------------------------------------------------------
__global__ __launch_bounds__(256, 3) void prep_kernel(
    const float* __restrict__ key, const float* __restrict__ value,
    const float* __restrict__ W, const float* __restrict__ b,
    unsigned short* __restrict__ projB, unsigned short* __restrict__ mpvB)
{
  __shared__ __align__(16) float Wl[64 * 64];
  __shared__ __align__(16) float pkv[68 * 68];  // K pool (rows 0..63), then V pool (68 rows)
  __shared__ __align__(16) float prL[64 * 68];
  __shared__ float coefs[64 * 4];               // c-1, c0, c+1 per local coarse row
  const int t = threadIdx.x;
  const int bid = blockIdx.x;
  const int bh = bid / 30;
  const int tt = bid % 30;
  int si, jt;
  if (tt < 16)      { si = 0; jt = tt; }
  else if (tt < 24) { si = 1; jt = tt - 16; }
  else if (tt < 28) { si = 2; jt = tt - 24; }
  else              { si = 3; jt = tt - 28; }
  const int s = 1 << si;
  const int L = 1024 >> si;
  const int off = (si == 0) ? 0 : (si == 1) ? 1024 : (si == 2) ? 1536 : 1792;
  const int j0 = jt << 6;
  const float invs = 1.0f / (float)s;

  // stage W[si]
  for (int i = t; i < 1024; i += 256)
    *(float4*)&Wl[i * 4] = *(const float4*)&W[si * 4096 + i * 4];

  // pool K rows j0..j0+63 (float4-vectorized)
  const float* Kp = key + bh * (S_LEN * DH);
  for (int i = t; i < 1024; i += 256) {
    const int j = i >> 4, d4 = (i & 15) << 2;
    const float* src = Kp + (j0 + j) * s * DH + d4;
    float4 a = {0.f, 0.f, 0.f, 0.f};
    for (int f = 0; f < s; f++) {
      const float4 kv = *(const float4*)(src + f * DH);
      a.x += kv.x; a.y += kv.y; a.z += kv.z; a.w += kv.w;
    }
    a.x *= invs; a.y *= invs; a.z *= invs; a.w *= invs;
    *(float4*)&pkv[j * 68 + d4] = a;
  }

  // tridiagonal stencil coefficients of M = U^T U for this block's 64 rows
  if (t < 64) {
    const int j = j0 + t;
    float cm = 0.f, cc = 0.f, cp = 0.f;
    const int klo = max(0, (j - 1) * s);
    const int khi = min(S_LEN - 1, (j + 2) * s);
    for (int kf = klo; kf <= khi; kf++) {
      float srcp = ((float)kf + 0.5f) * invs - 0.5f;
      srcp = fminf(fmaxf(srcp, 0.f), (float)(L - 1));
      const int i0 = (int)floorf(srcp);
      const int i1 = min(i0 + 1, L - 1);
      const float w = srcp - (float)i0;
      float u = 0.f;
      if (i0 == j) u += 1.f - w;
      if (i1 == j) u += w;
      if (u != 0.f) {
        const float g0 = u * (1.f - w), g1 = u * w;
        if (i0 == j) cc += g0; else cm += g0;   // i0 in {j-1, j}
        if (i1 == j) cc += g1; else cp += g1;   // i1 in {j, j+1}
      }
    }
    coefs[t * 4 + 0] = cm; coefs[t * 4 + 1] = cc; coefs[t * 4 + 2] = cp;
  }
  __syncthreads();

  // register-blocked projection: prL = pk @ W^T + b  (fp32)
  {
    const int j  = t & 63;
    const int e0 = (t >> 6) << 4;
    float acc[16];
    #pragma unroll
    for (int ee = 0; ee < 16; ee++) acc[ee] = b[si * 64 + e0 + ee];
    #pragma unroll
    for (int dq = 0; dq < 16; dq++) {
      const float4 p4 = *(const float4*)&pkv[j * 68 + dq * 4];
      #pragma unroll
      for (int ee = 0; ee < 16; ee++) {
        const float4 w4 = *(const float4*)&Wl[(e0 + ee) * 64 + dq * 4];
        acc[ee] += p4.x * w4.x + p4.y * w4.y + p4.z * w4.z + p4.w * w4.w;
      }
    }
    #pragma unroll
    for (int ee = 0; ee < 16; ee++) prL[j * 68 + e0 + ee] = acc[ee];
  }
  __syncthreads();   // prL ready; pkv dead -> reuse for pooled V

  // pool V rows j0-2 .. j0+65 (clamped) into pkv[68 rows]
  const float* Vp = value + bh * (S_LEN * DH);
  for (int i = t; i < 1088; i += 256) {
    const int hj = i >> 4, d4 = (i & 15) << 2;
    const int jg = min(max(j0 - 2 + hj, 0), L - 1);
    const float* src = Vp + jg * s * DH + d4;
    float4 a = {0.f, 0.f, 0.f, 0.f};
    for (int f = 0; f < s; f++) {
      const float4 vv = *(const float4*)(src + f * DH);
      a.x += vv.x; a.y += vv.y; a.z += vv.z; a.w += vv.w;
    }
    a.x *= invs; a.y *= invs; a.z *= invs; a.w *= invs;
    *(float4*)&pkv[hj * 68 + d4] = a;
  }

  // pack projB from prL (reads prL only; overlaps the V-pool loads above)
  const int ktg0 = (off + j0) >> 4;
  for (int c = t; c < 512; c += 256) {
    const int ktl = c >> 7;
    const int db  = (c >> 6) & 1;
    const int ln  = c & 63;
    const int kl  = ktl * 16 + (ln & 15);
    const int e0p = db * 32 + ((ln >> 4) & 3) * 8;
    const float4 a  = *(const float4*)&prL[kl * 68 + e0p];
    const float4 c4 = *(const float4*)&prL[kl * 68 + e0p + 4];
    bf8_t v;
    v[0] = (short)f2bf(a.x);  v[1] = (short)f2bf(a.y);
    v[2] = (short)f2bf(a.z);  v[3] = (short)f2bf(a.w);
    v[4] = (short)f2bf(c4.x); v[5] = (short)f2bf(c4.y);
    v[6] = (short)f2bf(c4.z); v[7] = (short)f2bf(c4.w);
    ((bf8_t*)projB)[bh * NCHUNK + ((ktg0 + ktl) * 2 + db) * 64 + ln] = v;
  }
  __syncthreads();   // pooled V ready

  // Mpv = stencil(pooled V), packed directly in MFMA-B frag order
  const int kbg0 = (off + j0) >> 5;
  for (int c = t; c < 512; c += 256) {
    const int kbl = c >> 8;              // 0..1
    const int nt  = (c >> 6) & 3;
    const int ln  = c & 63;
    const int d   = nt * 16 + (ln & 15);
    const int r0  = kbl * 32 + ((ln >> 4) & 3) * 8;
    bf8_t v;
    #pragma unroll
    for (int jj = 0; jj < 8; jj++) {
      const int rl = r0 + jj;
      const float cm = coefs[rl * 4 + 0];
      const float cc = coefs[rl * 4 + 1];
      const float cp = coefs[rl * 4 + 2];
      const float val = cm * pkv[(rl + 1) * 68 + d] +
                        cc * pkv[(rl + 2) * 68 + d] +
                        cp * pkv[(rl + 3) * 68 + d];
      v[jj] = (short)f2bf(val);
    }
    ((bf8_t*)mpvB)[bh * NCHUNK + ((kbg0 + kbl) * 4 + nt) * 64 + ln] = v;
  }
}

// ---------------------------------------------------------------------------
// FUSED: round-0 structure VERBATIM (measured 142 us; both restructures
// regressed it). 16 q-rows per block; grid = 64 q-tiles * 32 heads; 256 thr.
// ---------------------------------------------------------------------------
__global__ __launch_bounds__(256, 2) void fused_attn_kernel(
    const float* __restrict__ query, const unsigned short* __restrict__ projB,
    const unsigned short* __restrict__ mpvB, float* __restrict__ out)
{
  __shared__ __align__(16) unsigned short prbf[16 * PSTR];
  const int t    = threadIdx.x;
  const int bh   = blockIdx.x & 31;
  const int qt   = blockIdx.x >> 5;
  const int q0   = qt << 4;
  const int wave = t >> 6;
  const int lane = t & 63;
  const int quad = lane >> 4;
  const int n16  = lane & 15;

  // A-frags: A[m=lane&15][k=quad*8+j], k = d (+32 for second frag)
  bf8_t af0, af1;
  {
    const float* qrow = query + bh * (S_LEN * DH) + (q0 + n16) * DH;
    const float4 a0 = *(const float4*)(qrow + quad * 8);
    const float4 a1 = *(const float4*)(qrow + quad * 8 + 4);
    const float4 a2 = *(const float4*)(qrow + 32 + quad * 8);
    const float4 a3 = *(const float4*)(qrow + 32 + quad * 8 + 4);
    af0[0] = (short)f2bf(a0.x); af0[1] = (short)f2bf(a0.y);
    af0[2] = (short)f2bf(a0.z); af0[3] = (short)f2bf(a0.w);
    af0[4] = (short)f2bf(a1.x); af0[5] = (short)f2bf(a1.y);
    af0[6] = (short)f2bf(a1.z); af0[7] = (short)f2bf(a1.w);
    af1[0] = (short)f2bf(a2.x); af1[1] = (short)f2bf(a2.y);
    af1[2] = (short)f2bf(a2.z); af1[3] = (short)f2bf(a2.w);
    af1[4] = (short)f2bf(a3.x); af1[5] = (short)f2bf(a3.y);
    af1[6] = (short)f2bf(a3.z); af1[7] = (short)f2bf(a3.w);
  }

  // ---- P1: scores via MFMA; write bf16 to LDS ----
  {
    const bf8_t* pB = (const bf8_t*)projB + bh * NCHUNK;
    for (int kt = wave; kt < 120; kt += 4) {
      const bf8_t b0 = pB[(kt * 2 + 0) * 64 + lane];
      const bf8_t b1 = pB[(kt * 2 + 1) * 64 + lane];
      f32x4_t c = {0.f, 0.f, 0.f, 0.f};
      c = __builtin_amdgcn_mfma_f32_16x16x32_bf16(af0, b0, c, 0, 0, 0);
      c = __builtin_amdgcn_mfma_f32_16x16x32_bf16(af1, b1, c, 0, 0, 0);
      const int col = kt * 16 + n16;
      #pragma unroll
      for (int i = 0; i < 4; i++)
        prbf[(quad * 4 + i) * PSTR + col] = f2bf(c[i] * 0.125f);
    }
  }
  __syncthreads();

  // ---- P2: per-row per-scale softmax (bf16 in LDS, fp32 math) ----
  {
    const int rr = t >> 4;
    const int g  = t & 15;
    unsigned short* prr = prbf + rr * PSTR;
    #pragma unroll
    for (int si = 0; si < 4; si++) {
      const int L   = 1024 >> si;
      const int off = (si == 0) ? 0 : (si == 1) ? 1024 : (si == 2) ? 1536 : 1792;
      const int nch = L >> 2;
      float m = -1e30f;
      for (int ch = g; ch < nch; ch += 16) {
        const ushort4 u = *(const ushort4*)(prr + off + ch * 4);
        m = fmaxf(m, fmaxf(fmaxf(bf2f(u.x), bf2f(u.y)),
                           fmaxf(bf2f(u.z), bf2f(u.w))));
      }
      #pragma unroll
      for (int dlt = 8; dlt >= 1; dlt >>= 1) m = fmaxf(m, __shfl_xor(m, dlt));
      float ssum = 0.f;
      for (int ch = g; ch < nch; ch += 16) {
        ushort4 u = *(const ushort4*)(prr + off + ch * 4);
        const float e0 = __expf(bf2f(u.x) - m);
        const float e1 = __expf(bf2f(u.y) - m);
        const float e2 = __expf(bf2f(u.z) - m);
        const float e3 = __expf(bf2f(u.w) - m);
        ssum += (e0 + e1) + (e2 + e3);
        u.x = f2bf(e0); u.y = f2bf(e1); u.z = f2bf(e2); u.w = f2bf(e3);
        *(ushort4*)(prr + off + ch * 4) = u;
      }
      #pragma unroll
      for (int dlt = 8; dlt >= 1; dlt >>= 1) ssum += __shfl_xor(ssum, dlt);
      const float inv = 1.0f / ssum;
      for (int ch = g; ch < nch; ch += 16) {
        ushort4 u = *(const ushort4*)(prr + off + ch * 4);
        u.x = f2bf(bf2f(u.x) * inv); u.y = f2bf(bf2f(u.y) * inv);
        u.z = f2bf(bf2f(u.z) * inv); u.w = f2bf(bf2f(u.w) * inv);
        *(ushort4*)(prr + off + ch * 4) = u;
      }
    }
  }
  __syncthreads();

  // ---- P3: out = 0.25 * probs @ Mpv via MFMA (wave owns d-tile nt=wave) ----
  {
    const bf8_t* pM = (const bf8_t*)mpvB + bh * NCHUNK;
    f32x4_t acc = {0.f, 0.f, 0.f, 0.f};
    for (int kb = 0; kb < 60; kb++) {
      const bf8_t a = *(const bf8_t*)(prbf + n16 * PSTR + kb * 32 + quad * 8);
      const bf8_t bb = pM[(kb * 4 + wave) * 64 + lane];
      acc = __builtin_amdgcn_mfma_f32_16x16x32_bf16(a, bb, acc, 0, 0, 0);
    }
    float* ob = out + bh * (S_LEN * DH) + q0 * DH;
    #pragma unroll
    for (int i = 0; i < 4; i++)
      ob[(quad * 4 + i) * DH + wave * 16 + n16] = acc[i] * 0.25f;
  }

  // ---- P4: combined_attention = 0.25 * sum_s interp(probs_s) ----
  float* ab = out + ATTN_OFF + (size_t)bh * (S_LEN * S_LEN) + (size_t)q0 * S_LEN;
  for (int rep = 0; rep < 16; rep++) {
    const int idx = rep * 256 + t;        // float4 chunk id, 0..4095
    const int rr  = idx >> 8;
    const int k0  = (idx & 255) << 2;
    const unsigned short* p2 = prbf + rr * PSTR;
    const ushort4 bs = *(const ushort4*)(p2 + k0);
    float res[4] = {bf2f(bs.x), bf2f(bs.y), bf2f(bs.z), bf2f(bs.w)};
    #pragma unroll
    for (int si = 1; si < 4; si++) {
      const int   L     = 1024 >> si;
      const int   off2  = (si == 1) ? 1024 : (si == 2) ? 1536 : 1792;
      const float inv_s = (si == 1) ? 0.5f : (si == 2) ? 0.25f : 0.125f;
      #pragma unroll
      for (int kk = 0; kk < 4; kk++) {
        float srcp = ((float)(k0 + kk) + 0.5f) * inv_s - 0.5f;
        srcp = fminf(fmaxf(srcp, 0.f), (float)(L - 1));
        const int i0 = (int)floorf(srcp);
        const int i1 = min(i0 + 1, L - 1);
        const float w = srcp - (float)i0;
        res[kk] += (1.f - w) * bf2f(p2[off2 + i0]) + w * bf2f(p2[off2 + i1]);
      }
    }
    *(float4*)(ab + (size_t)idx * 4) =
        make_float4(res[0] * 0.25f, res[1] * 0.25f,
                    res[2] * 0.25f, res[3] * 0.25f);
  }
}

// ---------------------------------------------------------------------------
extern "C" void kernel_launch(void* const* d_in, const int* in_sizes, int n_in,
                              void* d_out, int out_size, void* d_ws, size_t ws_size,
                              hipStream_t stream) {
  (void)in_sizes; (void)n_in; (void)out_size; (void)ws_size;
  const float* query = (const float*)d_in[0];
  const float* key   = (const float*)d_in[1];
  const float* value = (const float*)d_in[2];
  const float* W     = (const float*)d_in[3];
  const float* b     = (const float*)d_in[4];
  float* out = (float*)d_out;

  unsigned short* projB = (unsigned short*)d_ws;                 // 7.9 MB bf16
  unsigned short* mpvB  = projB + (size_t)NBH * HEAD_K;          // 7.9 MB bf16

  prep_kernel<<<NBH * 30, 256, 0, stream>>>(key, value, W, b, projB, mpvB);
  fused_attn_kernel<<<NBH * 64, 256, 0, stream>>>(query, projB, mpvB, out);
}

// Round 5
// 307.782 us; speedup vs baseline: 1.3318x; 1.0090x over previous
//
#include <hip/hip_runtime.h>

#define S_LEN 1024
#define DH 64
#define NBH 32
#define CROWS 1920                   // 1024+512+256+128 coarse rows
#define HEAD_K (CROWS * DH)          // 122880 elements per head
#define NCHUNK (HEAD_K / 8)          // 15360 16-byte fragment chunks per head
#define ATTN_OFF (NBH * S_LEN * DH)  // start of combined_attention in d_out
#define PSTR 1928                    // LDS probs row stride (bf16 elems, padded)

typedef __attribute__((ext_vector_type(8))) short bf8_t;
typedef __attribute__((ext_vector_type(4))) float f32x4_t;

__device__ __forceinline__ unsigned short f2bf(float x) {
  unsigned u = __float_as_uint(x);
  u += 0x7fffu + ((u >> 16) & 1u);
  return (unsigned short)(u >> 16);
}
__device__ __forceinline__ float bf2f(unsigned short h) {
  return __uint_as_float(((unsigned)h) << 16);
}

// ---------------------------------------------------------------------------
// PREP body, templated on scale index SI so pooling loops fully unroll
// (runtime-s loops were serial load->add chains; that was ~all of prep's
// cost -- invariant across R1/R2/R3 prep variants at ~170us front-side).
// Phase A: pool K -> pkK, pool V(+-2 halo) -> pkV, stencil coefs.  (1 barrier)
// Phase B: projection from pkK with scalar-loaded W -> pack projB straight
//          from registers (no prL LDS round-trip); U^T U tridiagonal stencil
//          on pkV -> pack mpvB.
// ---------------------------------------------------------------------------
template<int SI>
__device__ __forceinline__ void prep_body(
    const float* __restrict__ key, const float* __restrict__ value,
    const float* __restrict__ W, const float* __restrict__ b,
    unsigned short* __restrict__ projB, unsigned short* __restrict__ mpvB,
    const int bh, const int jt, const int t,
    float* __restrict__ pkK, float* __restrict__ pkV, float* __restrict__ coefs)
{
  constexpr int   s    = 1 << SI;
  constexpr int   L    = 1024 >> SI;
  constexpr int   off  = (SI == 0) ? 0 : (SI == 1) ? 1024 : (SI == 2) ? 1536 : 1792;
  constexpr float invs = 1.0f / (float)s;
  const int j0 = jt << 6;

  const float* Kp = key + bh * (S_LEN * DH);
  const float* Vp = value + bh * (S_LEN * DH);

  // ---- pool K rows j0..j0+63 (unrolled: s independent loads in flight) ----
  #pragma unroll
  for (int it = 0; it < 4; it++) {
    const int i = it * 256 + t;
    const int j = i >> 4, d4 = (i & 15) << 2;
    const float* src = Kp + (j0 + j) * s * DH + d4;
    float4 a = {0.f, 0.f, 0.f, 0.f};
    #pragma unroll
    for (int f = 0; f < s; f++) {
      const float4 kv = *(const float4*)(src + f * DH);
      a.x += kv.x; a.y += kv.y; a.z += kv.z; a.w += kv.w;
    }
    a.x *= invs; a.y *= invs; a.z *= invs; a.w *= invs;
    *(float4*)&pkK[j * 68 + d4] = a;
  }

  // ---- pool V rows j0-2 .. j0+65 (clamped) into pkV[68 rows] ----
  #pragma unroll
  for (int it = 0; it < 5; it++) {
    const int i = it * 256 + t;
    if (i < 1088) {
      const int hj = i >> 4, d4 = (i & 15) << 2;
      const int jg = min(max(j0 - 2 + hj, 0), L - 1);
      const float* src = Vp + jg * s * DH + d4;
      float4 a = {0.f, 0.f, 0.f, 0.f};
      #pragma unroll
      for (int f = 0; f < s; f++) {
        const float4 vv = *(const float4*)(src + f * DH);
        a.x += vv.x; a.y += vv.y; a.z += vv.z; a.w += vv.w;
      }
      a.x *= invs; a.y *= invs; a.z *= invs; a.w *= invs;
      *(float4*)&pkV[hj * 68 + d4] = a;
    }
  }

  // ---- tridiagonal stencil coefficients of M = U^T U for 64 local rows ----
  if (t < 64) {
    const int j = j0 + t;
    float cm = 0.f, cc = 0.f, cp = 0.f;
    const int klo = max(0, (j - 1) * s);
    const int khi = min(S_LEN - 1, (j + 2) * s);
    for (int kf = klo; kf <= khi; kf++) {
      float srcp = ((float)kf + 0.5f) * invs - 0.5f;
      srcp = fminf(fmaxf(srcp, 0.f), (float)(L - 1));
      const int i0 = (int)floorf(srcp);
      const int i1 = min(i0 + 1, L - 1);
      const float w = srcp - (float)i0;
      float u = 0.f;
      if (i0 == j) u += 1.f - w;
      if (i1 == j) u += w;
      if (u != 0.f) {
        const float g0 = u * (1.f - w), g1 = u * w;
        if (i0 == j) cc += g0; else cm += g0;   // i0 in {j-1, j}
        if (i1 == j) cc += g1; else cp += g1;   // i1 in {j, j+1}
      }
    }
    coefs[t * 4 + 0] = cm; coefs[t * 4 + 1] = cc; coefs[t * 4 + 2] = cp;
  }
  __syncthreads();   // the only barrier

  // ---- projection: thread (j, e0) computes proj[j][e0..e0+15] in fp32, ----
  // ---- then packs its two 8-runs directly into projB (no LDS round-trip) --
  {
    const int j  = t & 63;
    const int e0 = __builtin_amdgcn_readfirstlane((t >> 6) << 4); // wave-uniform
    const float* Wp = W + SI * 4096;
    float acc[16];
    #pragma unroll
    for (int ee = 0; ee < 16; ee++) acc[ee] = b[SI * 64 + e0 + ee];
    #pragma unroll
    for (int dq = 0; dq < 16; dq++) {
      const float4 p4 = *(const float4*)&pkK[j * 68 + dq * 4];
      #pragma unroll
      for (int ee = 0; ee < 16; ee++) {
        const float4 w4 = *(const float4*)&Wp[(e0 + ee) * 64 + dq * 4]; // s_load
        acc[ee] += p4.x * w4.x + p4.y * w4.y + p4.z * w4.z + p4.w * w4.w;
      }
    }
    const int ktg0 = (off + j0) >> 4;
    const int ktl  = j >> 4;
    #pragma unroll
    for (int h = 0; h < 2; h++) {
      const int e0p = e0 + h * 8;
      const int ln  = (((e0p >> 3) & 3) << 4) | (j & 15);
      bf8_t v;
      #pragma unroll
      for (int jj = 0; jj < 8; jj++) v[jj] = (short)f2bf(acc[h * 8 + jj]);
      ((bf8_t*)projB)[bh * NCHUNK + ((ktg0 + ktl) * 2 + (e0p >> 5)) * 64 + ln] = v;
    }
  }

  // ---- Mpv = stencil(pooled V), packed directly in MFMA-B frag order ----
  const int kbg0 = (off + j0) >> 5;
  #pragma unroll
  for (int cc2 = 0; cc2 < 2; cc2++) {
    const int c   = cc2 * 256 + t;
    const int kbl = c >> 8;              // 0..1
    const int nt  = (c >> 6) & 3;
    const int ln  = c & 63;
    const int d   = nt * 16 + (ln & 15);
    const int r0  = kbl * 32 + ((ln >> 4) & 3) * 8;
    bf8_t v;
    #pragma unroll
    for (int jj = 0; jj < 8; jj++) {
      const int rl = r0 + jj;
      const float val = coefs[rl * 4 + 0] * pkV[(rl + 1) * 68 + d] +
                        coefs[rl * 4 + 1] * pkV[(rl + 2) * 68 + d] +
                        coefs[rl * 4 + 2] * pkV[(rl + 3) * 68 + d];
      v[jj] = (short)f2bf(val);
    }
    ((bf8_t*)mpvB)[bh * NCHUNK + ((kbg0 + kbl) * 4 + nt) * 64 + ln] = v;
  }
}

// LDS = pkK 17.4KB + pkV 18.5KB + coefs 1KB = 37KB -> 4 blocks/CU;
// all 960 blocks co-resident in one dispatch round.
__global__ __launch_bounds__(256, 4) void prep_kernel(
    const float* __restrict__ key, const float* __restrict__ value,
    const float* __restrict__ W, const float* __restrict__ b,
    unsigned short* __restrict__ projB, unsigned short* __restrict__ mpvB)
{
  __shared__ __align__(16) float pkK[64 * 68];
  __shared__ __align__(16) float pkV[68 * 68];
  __shared__ float coefs[64 * 4];
  const int t = threadIdx.x;
  const int bid = blockIdx.x;
  const int bh = bid / 30;
  const int tt = bid % 30;
  if (tt < 16)
    prep_body<0>(key, value, W, b, projB, mpvB, bh, tt, t, pkK, pkV, coefs);
  else if (tt < 24)
    prep_body<1>(key, value, W, b, projB, mpvB, bh, tt - 16, t, pkK, pkV, coefs);
  else if (tt < 28)
    prep_body<2>(key, value, W, b, projB, mpvB, bh, tt - 24, t, pkK, pkV, coefs);
  else
    prep_body<3>(key, value, W, b, projB, mpvB, bh, tt - 28, t, pkK, pkV, coefs);
}

// ---------------------------------------------------------------------------
// FUSED: round-0 structure VERBATIM (measured 142 us across three rounds;
// both restructures regressed it). 16 q-rows/block; grid = 64 q-tiles * 32 bh.
// ---------------------------------------------------------------------------
__global__ __launch_bounds__(256, 2) void fused_attn_kernel(
    const float* __restrict__ query, const unsigned short* __restrict__ projB,
    const unsigned short* __restrict__ mpvB, float* __restrict__ out)
{
  __shared__ __align__(16) unsigned short prbf[16 * PSTR];
  const int t    = threadIdx.x;
  const int bh   = blockIdx.x & 31;
  const int qt   = blockIdx.x >> 5;
  const int q0   = qt << 4;
  const int wave = t >> 6;
  const int lane = t & 63;
  const int quad = lane >> 4;
  const int n16  = lane & 15;

  // A-frags: A[m=lane&15][k=quad*8+j], k = d (+32 for second frag)
  bf8_t af0, af1;
  {
    const float* qrow = query + bh * (S_LEN * DH) + (q0 + n16) * DH;
    const float4 a0 = *(const float4*)(qrow + quad * 8);
    const float4 a1 = *(const float4*)(qrow + quad * 8 + 4);
    const float4 a2 = *(const float4*)(qrow + 32 + quad * 8);
    const float4 a3 = *(const float4*)(qrow + 32 + quad * 8 + 4);
    af0[0] = (short)f2bf(a0.x); af0[1] = (short)f2bf(a0.y);
    af0[2] = (short)f2bf(a0.z); af0[3] = (short)f2bf(a0.w);
    af0[4] = (short)f2bf(a1.x); af0[5] = (short)f2bf(a1.y);
    af0[6] = (short)f2bf(a1.z); af0[7] = (short)f2bf(a1.w);
    af1[0] = (short)f2bf(a2.x); af1[1] = (short)f2bf(a2.y);
    af1[2] = (short)f2bf(a2.z); af1[3] = (short)f2bf(a2.w);
    af1[4] = (short)f2bf(a3.x); af1[5] = (short)f2bf(a3.y);
    af1[6] = (short)f2bf(a3.z); af1[7] = (short)f2bf(a3.w);
  }

  // ---- P1: scores via MFMA; write bf16 to LDS ----
  {
    const bf8_t* pB = (const bf8_t*)projB + bh * NCHUNK;
    for (int kt = wave; kt < 120; kt += 4) {
      const bf8_t b0 = pB[(kt * 2 + 0) * 64 + lane];
      const bf8_t b1 = pB[(kt * 2 + 1) * 64 + lane];
      f32x4_t c = {0.f, 0.f, 0.f, 0.f};
      c = __builtin_amdgcn_mfma_f32_16x16x32_bf16(af0, b0, c, 0, 0, 0);
      c = __builtin_amdgcn_mfma_f32_16x16x32_bf16(af1, b1, c, 0, 0, 0);
      const int col = kt * 16 + n16;
      #pragma unroll
      for (int i = 0; i < 4; i++)
        prbf[(quad * 4 + i) * PSTR + col] = f2bf(c[i] * 0.125f);
    }
  }
  __syncthreads();

  // ---- P2: per-row per-scale softmax (bf16 in LDS, fp32 math) ----
  {
    const int rr = t >> 4;
    const int g  = t & 15;
    unsigned short* prr = prbf + rr * PSTR;
    #pragma unroll
    for (int si = 0; si < 4; si++) {
      const int L   = 1024 >> si;
      const int off = (si == 0) ? 0 : (si == 1) ? 1024 : (si == 2) ? 1536 : 1792;
      const int nch = L >> 2;
      float m = -1e30f;
      for (int ch = g; ch < nch; ch += 16) {
        const ushort4 u = *(const ushort4*)(prr + off + ch * 4);
        m = fmaxf(m, fmaxf(fmaxf(bf2f(u.x), bf2f(u.y)),
                           fmaxf(bf2f(u.z), bf2f(u.w))));
      }
      #pragma unroll
      for (int dlt = 8; dlt >= 1; dlt >>= 1) m = fmaxf(m, __shfl_xor(m, dlt));
      float ssum = 0.f;
      for (int ch = g; ch < nch; ch += 16) {
        ushort4 u = *(const ushort4*)(prr + off + ch * 4);
        const float e0 = __expf(bf2f(u.x) - m);
        const float e1 = __expf(bf2f(u.y) - m);
        const float e2 = __expf(bf2f(u.z) - m);
        const float e3 = __expf(bf2f(u.w) - m);
        ssum += (e0 + e1) + (e2 + e3);
        u.x = f2bf(e0); u.y = f2bf(e1); u.z = f2bf(e2); u.w = f2bf(e3);
        *(ushort4*)(prr + off + ch * 4) = u;
      }
      #pragma unroll
      for (int dlt = 8; dlt >= 1; dlt >>= 1) ssum += __shfl_xor(ssum, dlt);
      const float inv = 1.0f / ssum;
      for (int ch = g; ch < nch; ch += 16) {
        ushort4 u = *(const ushort4*)(prr + off + ch * 4);
        u.x = f2bf(bf2f(u.x) * inv); u.y = f2bf(bf2f(u.y) * inv);
        u.z = f2bf(bf2f(u.z) * inv); u.w = f2bf(bf2f(u.w) * inv);
        *(ushort4*)(prr + off + ch * 4) = u;
      }
    }
  }
  __syncthreads();

  // ---- P3: out = 0.25 * probs @ Mpv via MFMA (wave owns d-tile nt=wave) ----
  {
    const bf8_t* pM = (const bf8_t*)mpvB + bh * NCHUNK;
    f32x4_t acc = {0.f, 0.f, 0.f, 0.f};
    for (int kb = 0; kb < 60; kb++) {
      const bf8_t a = *(const bf8_t*)(prbf + n16 * PSTR + kb * 32 + quad * 8);
      const bf8_t bb = pM[(kb * 4 + wave) * 64 + lane];
      acc = __builtin_amdgcn_mfma_f32_16x16x32_bf16(a, bb, acc, 0, 0, 0);
    }
    float* ob = out + bh * (S_LEN * DH) + q0 * DH;
    #pragma unroll
    for (int i = 0; i < 4; i++)
      ob[(quad * 4 + i) * DH + wave * 16 + n16] = acc[i] * 0.25f;
  }

  // ---- P4: combined_attention = 0.25 * sum_s interp(probs_s) ----
  float* ab = out + ATTN_OFF + (size_t)bh * (S_LEN * S_LEN) + (size_t)q0 * S_LEN;
  for (int rep = 0; rep < 16; rep++) {
    const int idx = rep * 256 + t;        // float4 chunk id, 0..4095
    const int rr  = idx >> 8;
    const int k0  = (idx & 255) << 2;
    const unsigned short* p2 = prbf + rr * PSTR;
    const ushort4 bs = *(const ushort4*)(p2 + k0);
    float res[4] = {bf2f(bs.x), bf2f(bs.y), bf2f(bs.z), bf2f(bs.w)};
    #pragma unroll
    for (int si = 1; si < 4; si++) {
      const int   L     = 1024 >> si;
      const int   off2  = (si == 1) ? 1024 : (si == 2) ? 1536 : 1792;
      const float inv_s = (si == 1) ? 0.5f : (si == 2) ? 0.25f : 0.125f;
      #pragma unroll
      for (int kk = 0; kk < 4; kk++) {
        float srcp = ((float)(k0 + kk) + 0.5f) * inv_s - 0.5f;
        srcp = fminf(fmaxf(srcp, 0.f), (float)(L - 1));
        const int i0 = (int)floorf(srcp);
        const int i1 = min(i0 + 1, L - 1);
        const float w = srcp - (float)i0;
        res[kk] += (1.f - w) * bf2f(p2[off2 + i0]) + w * bf2f(p2[off2 + i1]);
      }
    }
    *(float4*)(ab + (size_t)idx * 4) =
        make_float4(res[0] * 0.25f, res[1] * 0.25f,
                    res[2] * 0.25f, res[3] * 0.25f);
  }
}

// ---------------------------------------------------------------------------
extern "C" void kernel_launch(void* const* d_in, const int* in_sizes, int n_in,
                              void* d_out, int out_size, void* d_ws, size_t ws_size,
                              hipStream_t stream) {
  (void)in_sizes; (void)n_in; (void)out_size; (void)ws_size;
  const float* query = (const float*)d_in[0];
  const float* key   = (const float*)d_in[1];
  const float* value = (const float*)d_in[2];
  const float* W     = (const float*)d_in[3];
  const float* b     = (const float*)d_in[4];
  float* out = (float*)d_out;

  unsigned short* projB = (unsigned short*)d_ws;                 // 7.9 MB bf16
  unsigned short* mpvB  = projB + (size_t)NBH * HEAD_K;          // 7.9 MB bf16

  prep_kernel<<<NBH * 30, 256, 0, stream>>>(key, value, W, b, projB, mpvB);
  fused_attn_kernel<<<NBH * 64, 256, 0, stream>>>(query, projB, mpvB, out);
}

// Round 7
// 294.916 us; speedup vs baseline: 1.3898x; 1.0436x over previous
//
#include <hip/hip_runtime.h>

#define S_LEN 1024
#define DH 64
#define NBH 32
#define CROWS 1920                   // 1024+512+256+128 coarse rows
#define HEAD_K (CROWS * DH)          // 122880 elements per head
#define NCHUNK (HEAD_K / 8)          // 15360 16-byte fragment chunks per head
#define ATTN_OFF (NBH * S_LEN * DH)  // start of combined_attention in d_out
#define PSTR 1928                    // LDS probs row stride (bf16 elems, padded)

typedef __attribute__((ext_vector_type(8))) short bf8_t;
typedef __attribute__((ext_vector_type(4))) float f32x4_t;

__device__ __forceinline__ unsigned short f2bf(float x) {
  unsigned u = __float_as_uint(x);
  u += 0x7fffu + ((u >> 16) & 1u);
  return (unsigned short)(u >> 16);
}
__device__ __forceinline__ float bf2f(unsigned short h) {
  return __uint_as_float(((unsigned)h) << 16);
}

// ---------------------------------------------------------------------------
// PREP body, templated on scale index SI (unchanged from R5; prep is ~20us,
// front side is dominated by fixed harness overhead -- proven R2/R3/R5).
// ---------------------------------------------------------------------------
template<int SI>
__device__ __forceinline__ void prep_body(
    const float* __restrict__ key, const float* __restrict__ value,
    const float* __restrict__ W, const float* __restrict__ b,
    unsigned short* __restrict__ projB, unsigned short* __restrict__ mpvB,
    const int bh, const int jt, const int t,
    float* __restrict__ pkK, float* __restrict__ pkV, float* __restrict__ coefs)
{
  constexpr int   s    = 1 << SI;
  constexpr int   L    = 1024 >> SI;
  constexpr int   off  = (SI == 0) ? 0 : (SI == 1) ? 1024 : (SI == 2) ? 1536 : 1792;
  constexpr float invs = 1.0f / (float)s;
  const int j0 = jt << 6;

  const float* Kp = key + bh * (S_LEN * DH);
  const float* Vp = value + bh * (S_LEN * DH);

  // ---- pool K rows j0..j0+63 (unrolled: s independent loads in flight) ----
  #pragma unroll
  for (int it = 0; it < 4; it++) {
    const int i = it * 256 + t;
    const int j = i >> 4, d4 = (i & 15) << 2;
    const float* src = Kp + (j0 + j) * s * DH + d4;
    float4 a = {0.f, 0.f, 0.f, 0.f};
    #pragma unroll
    for (int f = 0; f < s; f++) {
      const float4 kv = *(const float4*)(src + f * DH);
      a.x += kv.x; a.y += kv.y; a.z += kv.z; a.w += kv.w;
    }
    a.x *= invs; a.y *= invs; a.z *= invs; a.w *= invs;
    *(float4*)&pkK[j * 68 + d4] = a;
  }

  // ---- pool V rows j0-2 .. j0+65 (clamped) into pkV[68 rows] ----
  #pragma unroll
  for (int it = 0; it < 5; it++) {
    const int i = it * 256 + t;
    if (i < 1088) {
      const int hj = i >> 4, d4 = (i & 15) << 2;
      const int jg = min(max(j0 - 2 + hj, 0), L - 1);
      const float* src = Vp + jg * s * DH + d4;
      float4 a = {0.f, 0.f, 0.f, 0.f};
      #pragma unroll
      for (int f = 0; f < s; f++) {
        const float4 vv = *(const float4*)(src + f * DH);
        a.x += vv.x; a.y += vv.y; a.z += vv.z; a.w += vv.w;
      }
      a.x *= invs; a.y *= invs; a.z *= invs; a.w *= invs;
      *(float4*)&pkV[hj * 68 + d4] = a;
    }
  }

  // ---- tridiagonal stencil coefficients of M = U^T U for 64 local rows ----
  if (t < 64) {
    const int j = j0 + t;
    float cm = 0.f, cc = 0.f, cp = 0.f;
    const int klo = max(0, (j - 1) * s);
    const int khi = min(S_LEN - 1, (j + 2) * s);
    for (int kf = klo; kf <= khi; kf++) {
      float srcp = ((float)kf + 0.5f) * invs - 0.5f;
      srcp = fminf(fmaxf(srcp, 0.f), (float)(L - 1));
      const int i0 = (int)floorf(srcp);
      const int i1 = min(i0 + 1, L - 1);
      const float w = srcp - (float)i0;
      float u = 0.f;
      if (i0 == j) u += 1.f - w;
      if (i1 == j) u += w;
      if (u != 0.f) {
        const float g0 = u * (1.f - w), g1 = u * w;
        if (i0 == j) cc += g0; else cm += g0;   // i0 in {j-1, j}
        if (i1 == j) cc += g1; else cp += g1;   // i1 in {j, j+1}
      }
    }
    coefs[t * 4 + 0] = cm; coefs[t * 4 + 1] = cc; coefs[t * 4 + 2] = cp;
  }
  __syncthreads();   // the only barrier

  // ---- projection: thread (j, e0) computes proj[j][e0..e0+15] in fp32, ----
  // ---- then packs its two 8-runs directly into projB (no LDS round-trip) --
  {
    const int j  = t & 63;
    const int e0 = __builtin_amdgcn_readfirstlane((t >> 6) << 4); // wave-uniform
    const float* Wp = W + SI * 4096;
    float acc[16];
    #pragma unroll
    for (int ee = 0; ee < 16; ee++) acc[ee] = b[SI * 64 + e0 + ee];
    #pragma unroll
    for (int dq = 0; dq < 16; dq++) {
      const float4 p4 = *(const float4*)&pkK[j * 68 + dq * 4];
      #pragma unroll
      for (int ee = 0; ee < 16; ee++) {
        const float4 w4 = *(const float4*)&Wp[(e0 + ee) * 64 + dq * 4]; // s_load
        acc[ee] += p4.x * w4.x + p4.y * w4.y + p4.z * w4.z + p4.w * w4.w;
      }
    }
    const int ktg0 = (off + j0) >> 4;
    const int ktl  = j >> 4;
    #pragma unroll
    for (int h = 0; h < 2; h++) {
      const int e0p = e0 + h * 8;
      const int ln  = (((e0p >> 3) & 3) << 4) | (j & 15);
      bf8_t v;
      #pragma unroll
      for (int jj = 0; jj < 8; jj++) v[jj] = (short)f2bf(acc[h * 8 + jj]);
      ((bf8_t*)projB)[bh * NCHUNK + ((ktg0 + ktl) * 2 + (e0p >> 5)) * 64 + ln] = v;
    }
  }

  // ---- Mpv = stencil(pooled V), packed directly in MFMA-B frag order ----
  const int kbg0 = (off + j0) >> 5;
  #pragma unroll
  for (int cc2 = 0; cc2 < 2; cc2++) {
    const int c   = cc2 * 256 + t;
    const int kbl = c >> 8;              // 0..1
    const int nt  = (c >> 6) & 3;
    const int ln  = c & 63;
    const int d   = nt * 16 + (ln & 15);
    const int r0  = kbl * 32 + ((ln >> 4) & 3) * 8;
    bf8_t v;
    #pragma unroll
    for (int jj = 0; jj < 8; jj++) {
      const int rl = r0 + jj;
      const float val = coefs[rl * 4 + 0] * pkV[(rl + 1) * 68 + d] +
                        coefs[rl * 4 + 1] * pkV[(rl + 2) * 68 + d] +
                        coefs[rl * 4 + 2] * pkV[(rl + 3) * 68 + d];
      v[jj] = (short)f2bf(val);
    }
    ((bf8_t*)mpvB)[bh * NCHUNK + ((kbg0 + kbl) * 4 + nt) * 64 + ln] = v;
  }
}

// LDS = pkK 17.4KB + pkV 18.5KB + coefs 1KB = 37KB -> 4 blocks/CU.
__global__ __launch_bounds__(256, 4) void prep_kernel(
    const float* __restrict__ key, const float* __restrict__ value,
    const float* __restrict__ W, const float* __restrict__ b,
    unsigned short* __restrict__ projB, unsigned short* __restrict__ mpvB)
{
  __shared__ __align__(16) float pkK[64 * 68];
  __shared__ __align__(16) float pkV[68 * 68];
  __shared__ float coefs[64 * 4];
  const int t = threadIdx.x;
  const int bid = blockIdx.x;
  const int bh = bid / 30;
  const int tt = bid % 30;
  if (tt < 16)
    prep_body<0>(key, value, W, b, projB, mpvB, bh, tt, t, pkK, pkV, coefs);
  else if (tt < 24)
    prep_body<1>(key, value, W, b, projB, mpvB, bh, tt - 16, t, pkK, pkV, coefs);
  else if (tt < 28)
    prep_body<2>(key, value, W, b, projB, mpvB, bh, tt - 24, t, pkK, pkV, coefs);
  else
    prep_body<3>(key, value, W, b, projB, mpvB, bh, tt - 28, t, pkK, pkV, coefs);
}

// ---------------------------------------------------------------------------
// FUSED: round-0 phase structure VERBATIM (142us, thrice-reproduced).
// Memory-system-local changes only:
//  (a) XCD-aware swizzle: XCD x (= bid&7, round-robin dispatch) gets heads
//      4x..4x+3 -> per-XCD L2 working set 1.96MB < 4MB (was 15.7MB).
//  (b) depth-2 register prefetch of global B-frags in P1/P3.
//  (c) non-temporal stores for the 136MB streamed output (f32x4_t, not
//      HIP float4 -- __builtin_nontemporal_store requires a clang vector).
// ---------------------------------------------------------------------------
__global__ __launch_bounds__(256, 2) void fused_attn_kernel(
    const float* __restrict__ query, const unsigned short* __restrict__ projB,
    const unsigned short* __restrict__ mpvB, float* __restrict__ out)
{
  __shared__ __align__(16) unsigned short prbf[16 * PSTR];
  const int t    = threadIdx.x;
  // XCD-aware bh-colocating swizzle (bijective: 2048 = 8 xcd * 4 bh * 64 qt)
  const int bid  = blockIdx.x;
  const int xcd  = bid & 7;
  const int slot = bid >> 3;              // 0..255 within this XCD's share
  const int bh   = xcd * 4 + (slot >> 6); // 4 consecutive heads per XCD
  const int qt   = slot & 63;
  const int q0   = qt << 4;
  const int wave = t >> 6;
  const int lane = t & 63;
  const int quad = lane >> 4;
  const int n16  = lane & 15;

  // A-frags: A[m=lane&15][k=quad*8+j], k = d (+32 for second frag)
  bf8_t af0, af1;
  {
    const float* qrow = query + bh * (S_LEN * DH) + (q0 + n16) * DH;
    const float4 a0 = *(const float4*)(qrow + quad * 8);
    const float4 a1 = *(const float4*)(qrow + quad * 8 + 4);
    const float4 a2 = *(const float4*)(qrow + 32 + quad * 8);
    const float4 a3 = *(const float4*)(qrow + 32 + quad * 8 + 4);
    af0[0] = (short)f2bf(a0.x); af0[1] = (short)f2bf(a0.y);
    af0[2] = (short)f2bf(a0.z); af0[3] = (short)f2bf(a0.w);
    af0[4] = (short)f2bf(a1.x); af0[5] = (short)f2bf(a1.y);
    af0[6] = (short)f2bf(a1.z); af0[7] = (short)f2bf(a1.w);
    af1[0] = (short)f2bf(a2.x); af1[1] = (short)f2bf(a2.y);
    af1[2] = (short)f2bf(a2.z); af1[3] = (short)f2bf(a2.w);
    af1[4] = (short)f2bf(a3.x); af1[5] = (short)f2bf(a3.y);
    af1[6] = (short)f2bf(a3.z); af1[7] = (short)f2bf(a3.w);
  }

  // ---- P1: scores via MFMA; write bf16 to LDS (depth-2 global prefetch) ----
  {
    const bf8_t* pB = (const bf8_t*)projB + bh * NCHUNK;
    bf8_t pb0 = pB[(wave * 2 + 0) * 64 + lane];
    bf8_t pb1 = pB[(wave * 2 + 1) * 64 + lane];
    for (int kt = wave; kt < 120; kt += 4) {
      const int ktn = min(kt + 4, 119);       // tail prefetch clamped (re-read)
      const bf8_t nb0 = pB[(ktn * 2 + 0) * 64 + lane];
      const bf8_t nb1 = pB[(ktn * 2 + 1) * 64 + lane];
      f32x4_t c = {0.f, 0.f, 0.f, 0.f};
      c = __builtin_amdgcn_mfma_f32_16x16x32_bf16(af0, pb0, c, 0, 0, 0);
      c = __builtin_amdgcn_mfma_f32_16x16x32_bf16(af1, pb1, c, 0, 0, 0);
      const int col = kt * 16 + n16;
      #pragma unroll
      for (int i = 0; i < 4; i++)
        prbf[(quad * 4 + i) * PSTR + col] = f2bf(c[i] * 0.125f);
      pb0 = nb0; pb1 = nb1;
    }
  }
  __syncthreads();

  // ---- P2: per-row per-scale softmax (bf16 in LDS, fp32 math) ----
  {
    const int rr = t >> 4;
    const int g  = t & 15;
    unsigned short* prr = prbf + rr * PSTR;
    #pragma unroll
    for (int si = 0; si < 4; si++) {
      const int L   = 1024 >> si;
      const int off = (si == 0) ? 0 : (si == 1) ? 1024 : (si == 2) ? 1536 : 1792;
      const int nch = L >> 2;
      float m = -1e30f;
      for (int ch = g; ch < nch; ch += 16) {
        const ushort4 u = *(const ushort4*)(prr + off + ch * 4);
        m = fmaxf(m, fmaxf(fmaxf(bf2f(u.x), bf2f(u.y)),
                           fmaxf(bf2f(u.z), bf2f(u.w))));
      }
      #pragma unroll
      for (int dlt = 8; dlt >= 1; dlt >>= 1) m = fmaxf(m, __shfl_xor(m, dlt));
      float ssum = 0.f;
      for (int ch = g; ch < nch; ch += 16) {
        ushort4 u = *(const ushort4*)(prr + off + ch * 4);
        const float e0 = __expf(bf2f(u.x) - m);
        const float e1 = __expf(bf2f(u.y) - m);
        const float e2 = __expf(bf2f(u.z) - m);
        const float e3 = __expf(bf2f(u.w) - m);
        ssum += (e0 + e1) + (e2 + e3);
        u.x = f2bf(e0); u.y = f2bf(e1); u.z = f2bf(e2); u.w = f2bf(e3);
        *(ushort4*)(prr + off + ch * 4) = u;
      }
      #pragma unroll
      for (int dlt = 8; dlt >= 1; dlt >>= 1) ssum += __shfl_xor(ssum, dlt);
      const float inv = 1.0f / ssum;
      for (int ch = g; ch < nch; ch += 16) {
        ushort4 u = *(const ushort4*)(prr + off + ch * 4);
        u.x = f2bf(bf2f(u.x) * inv); u.y = f2bf(bf2f(u.y) * inv);
        u.z = f2bf(bf2f(u.z) * inv); u.w = f2bf(bf2f(u.w) * inv);
        *(ushort4*)(prr + off + ch * 4) = u;
      }
    }
  }
  __syncthreads();

  // ---- P3: out = 0.25 * probs @ Mpv via MFMA (depth-2 global prefetch) ----
  {
    const bf8_t* pM = (const bf8_t*)mpvB + bh * NCHUNK;
    f32x4_t acc = {0.f, 0.f, 0.f, 0.f};
    bf8_t bb0 = pM[(0 * 4 + wave) * 64 + lane];
    bf8_t bb1 = pM[(1 * 4 + wave) * 64 + lane];
    for (int kb = 0; kb < 60; kb++) {
      const int kbn = min(kb + 2, 59);        // tail prefetch clamped (re-read)
      const bf8_t bbn = pM[(kbn * 4 + wave) * 64 + lane];
      const bf8_t a = *(const bf8_t*)(prbf + n16 * PSTR + kb * 32 + quad * 8);
      acc = __builtin_amdgcn_mfma_f32_16x16x32_bf16(a, bb0, acc, 0, 0, 0);
      bb0 = bb1; bb1 = bbn;
    }
    float* ob = out + bh * (S_LEN * DH) + q0 * DH;
    #pragma unroll
    for (int i = 0; i < 4; i++)
      __builtin_nontemporal_store(acc[i] * 0.25f,
                                  &ob[(quad * 4 + i) * DH + wave * 16 + n16]);
  }

  // ---- P4: combined_attention = 0.25 * sum_s interp(probs_s) ----
  float* ab = out + ATTN_OFF + (size_t)bh * (S_LEN * S_LEN) + (size_t)q0 * S_LEN;
  for (int rep = 0; rep < 16; rep++) {
    const int idx = rep * 256 + t;        // float4 chunk id, 0..4095
    const int rr  = idx >> 8;
    const int k0  = (idx & 255) << 2;
    const unsigned short* p2 = prbf + rr * PSTR;
    const ushort4 bs = *(const ushort4*)(p2 + k0);
    float res[4] = {bf2f(bs.x), bf2f(bs.y), bf2f(bs.z), bf2f(bs.w)};
    #pragma unroll
    for (int si = 1; si < 4; si++) {
      const int   L     = 1024 >> si;
      const int   off2  = (si == 1) ? 1024 : (si == 2) ? 1536 : 1792;
      const float inv_s = (si == 1) ? 0.5f : (si == 2) ? 0.25f : 0.125f;
      #pragma unroll
      for (int kk = 0; kk < 4; kk++) {
        float srcp = ((float)(k0 + kk) + 0.5f) * inv_s - 0.5f;
        srcp = fminf(fmaxf(srcp, 0.f), (float)(L - 1));
        const int i0 = (int)floorf(srcp);
        const int i1 = min(i0 + 1, L - 1);
        const float w = srcp - (float)i0;
        res[kk] += (1.f - w) * bf2f(p2[off2 + i0]) + w * bf2f(p2[off2 + i1]);
      }
    }
    f32x4_t o4;
    o4[0] = res[0] * 0.25f; o4[1] = res[1] * 0.25f;
    o4[2] = res[2] * 0.25f; o4[3] = res[3] * 0.25f;
    __builtin_nontemporal_store(o4, (f32x4_t*)(ab + (size_t)idx * 4));
  }
}

// ---------------------------------------------------------------------------
extern "C" void kernel_launch(void* const* d_in, const int* in_sizes, int n_in,
                              void* d_out, int out_size, void* d_ws, size_t ws_size,
                              hipStream_t stream) {
  (void)in_sizes; (void)n_in; (void)out_size; (void)ws_size;
  const float* query = (const float*)d_in[0];
  const float* key   = (const float*)d_in[1];
  const float* value = (const float*)d_in[2];
  const float* W     = (const float*)d_in[3];
  const float* b     = (const float*)d_in[4];
  float* out = (float*)d_out;

  unsigned short* projB = (unsigned short*)d_ws;                 // 7.9 MB bf16
  unsigned short* mpvB  = projB + (size_t)NBH * HEAD_K;          // 7.9 MB bf16

  prep_kernel<<<NBH * 30, 256, 0, stream>>>(key, value, W, b, projB, mpvB);
  fused_attn_kernel<<<NBH * 64, 256, 0, stream>>>(query, projB, mpvB, out);
}

// Round 8
// 286.491 us; speedup vs baseline: 1.4307x; 1.0294x over previous
//
#include <hip/hip_runtime.h>

#define S_LEN 1024
#define DH 64
#define NBH 32
#define CROWS 1920                   // 1024+512+256+128 coarse rows
#define HEAD_K (CROWS * DH)          // 122880 elements per head
#define NCHUNK (HEAD_K / 8)          // 15360 16-byte fragment chunks per head
#define ATTN_OFF (NBH * S_LEN * DH)  // start of combined_attention in d_out
#define PSTR 1928                    // LDS probs row stride (bf16 elems, padded)

typedef __attribute__((ext_vector_type(8))) short bf8_t;
typedef __attribute__((ext_vector_type(4))) float f32x4_t;

__device__ __forceinline__ unsigned short f2bf(float x) {
  unsigned u = __float_as_uint(x);
  u += 0x7fffu + ((u >> 16) & 1u);
  return (unsigned short)(u >> 16);
}
__device__ __forceinline__ float bf2f(unsigned short h) {
  return __uint_as_float(((unsigned)h) << 16);
}

// ---------------------------------------------------------------------------
// PREP body, templated on scale index SI (unchanged from R5/R7).
// ---------------------------------------------------------------------------
template<int SI>
__device__ __forceinline__ void prep_body(
    const float* __restrict__ key, const float* __restrict__ value,
    const float* __restrict__ W, const float* __restrict__ b,
    unsigned short* __restrict__ projB, unsigned short* __restrict__ mpvB,
    const int bh, const int jt, const int t,
    float* __restrict__ pkK, float* __restrict__ pkV, float* __restrict__ coefs)
{
  constexpr int   s    = 1 << SI;
  constexpr int   L    = 1024 >> SI;
  constexpr int   off  = (SI == 0) ? 0 : (SI == 1) ? 1024 : (SI == 2) ? 1536 : 1792;
  constexpr float invs = 1.0f / (float)s;
  const int j0 = jt << 6;

  const float* Kp = key + bh * (S_LEN * DH);
  const float* Vp = value + bh * (S_LEN * DH);

  // ---- pool K rows j0..j0+63 (unrolled: s independent loads in flight) ----
  #pragma unroll
  for (int it = 0; it < 4; it++) {
    const int i = it * 256 + t;
    const int j = i >> 4, d4 = (i & 15) << 2;
    const float* src = Kp + (j0 + j) * s * DH + d4;
    float4 a = {0.f, 0.f, 0.f, 0.f};
    #pragma unroll
    for (int f = 0; f < s; f++) {
      const float4 kv = *(const float4*)(src + f * DH);
      a.x += kv.x; a.y += kv.y; a.z += kv.z; a.w += kv.w;
    }
    a.x *= invs; a.y *= invs; a.z *= invs; a.w *= invs;
    *(float4*)&pkK[j * 68 + d4] = a;
  }

  // ---- pool V rows j0-2 .. j0+65 (clamped) into pkV[68 rows] ----
  #pragma unroll
  for (int it = 0; it < 5; it++) {
    const int i = it * 256 + t;
    if (i < 1088) {
      const int hj = i >> 4, d4 = (i & 15) << 2;
      const int jg = min(max(j0 - 2 + hj, 0), L - 1);
      const float* src = Vp + jg * s * DH + d4;
      float4 a = {0.f, 0.f, 0.f, 0.f};
      #pragma unroll
      for (int f = 0; f < s; f++) {
        const float4 vv = *(const float4*)(src + f * DH);
        a.x += vv.x; a.y += vv.y; a.z += vv.z; a.w += vv.w;
      }
      a.x *= invs; a.y *= invs; a.z *= invs; a.w *= invs;
      *(float4*)&pkV[hj * 68 + d4] = a;
    }
  }

  // ---- tridiagonal stencil coefficients of M = U^T U for 64 local rows ----
  if (t < 64) {
    const int j = j0 + t;
    float cm = 0.f, cc = 0.f, cp = 0.f;
    const int klo = max(0, (j - 1) * s);
    const int khi = min(S_LEN - 1, (j + 2) * s);
    for (int kf = klo; kf <= khi; kf++) {
      float srcp = ((float)kf + 0.5f) * invs - 0.5f;
      srcp = fminf(fmaxf(srcp, 0.f), (float)(L - 1));
      const int i0 = (int)floorf(srcp);
      const int i1 = min(i0 + 1, L - 1);
      const float w = srcp - (float)i0;
      float u = 0.f;
      if (i0 == j) u += 1.f - w;
      if (i1 == j) u += w;
      if (u != 0.f) {
        const float g0 = u * (1.f - w), g1 = u * w;
        if (i0 == j) cc += g0; else cm += g0;   // i0 in {j-1, j}
        if (i1 == j) cc += g1; else cp += g1;   // i1 in {j, j+1}
      }
    }
    coefs[t * 4 + 0] = cm; coefs[t * 4 + 1] = cc; coefs[t * 4 + 2] = cp;
  }
  __syncthreads();   // the only barrier

  // ---- projection: thread (j, e0) computes proj[j][e0..e0+15] in fp32, ----
  // ---- then packs its two 8-runs directly into projB (no LDS round-trip) --
  {
    const int j  = t & 63;
    const int e0 = __builtin_amdgcn_readfirstlane((t >> 6) << 4); // wave-uniform
    const float* Wp = W + SI * 4096;
    float acc[16];
    #pragma unroll
    for (int ee = 0; ee < 16; ee++) acc[ee] = b[SI * 64 + e0 + ee];
    #pragma unroll
    for (int dq = 0; dq < 16; dq++) {
      const float4 p4 = *(const float4*)&pkK[j * 68 + dq * 4];
      #pragma unroll
      for (int ee = 0; ee < 16; ee++) {
        const float4 w4 = *(const float4*)&Wp[(e0 + ee) * 64 + dq * 4]; // s_load
        acc[ee] += p4.x * w4.x + p4.y * w4.y + p4.z * w4.z + p4.w * w4.w;
      }
    }
    const int ktg0 = (off + j0) >> 4;
    const int ktl  = j >> 4;
    #pragma unroll
    for (int h = 0; h < 2; h++) {
      const int e0p = e0 + h * 8;
      const int ln  = (((e0p >> 3) & 3) << 4) | (j & 15);
      bf8_t v;
      #pragma unroll
      for (int jj = 0; jj < 8; jj++) v[jj] = (short)f2bf(acc[h * 8 + jj]);
      ((bf8_t*)projB)[bh * NCHUNK + ((ktg0 + ktl) * 2 + (e0p >> 5)) * 64 + ln] = v;
    }
  }

  // ---- Mpv = stencil(pooled V), packed directly in MFMA-B frag order ----
  const int kbg0 = (off + j0) >> 5;
  #pragma unroll
  for (int cc2 = 0; cc2 < 2; cc2++) {
    const int c   = cc2 * 256 + t;
    const int kbl = c >> 8;              // 0..1
    const int nt  = (c >> 6) & 3;
    const int ln  = c & 63;
    const int d   = nt * 16 + (ln & 15);
    const int r0  = kbl * 32 + ((ln >> 4) & 3) * 8;
    bf8_t v;
    #pragma unroll
    for (int jj = 0; jj < 8; jj++) {
      const int rl = r0 + jj;
      const float val = coefs[rl * 4 + 0] * pkV[(rl + 1) * 68 + d] +
                        coefs[rl * 4 + 1] * pkV[(rl + 2) * 68 + d] +
                        coefs[rl * 4 + 2] * pkV[(rl + 3) * 68 + d];
      v[jj] = (short)f2bf(val);
    }
    ((bf8_t*)mpvB)[bh * NCHUNK + ((kbg0 + kbl) * 4 + nt) * 64 + ln] = v;
  }
}

// LDS = pkK 17.4KB + pkV 18.5KB + coefs 1KB = 37KB -> 4 blocks/CU.
__global__ __launch_bounds__(256, 4) void prep_kernel(
    const float* __restrict__ key, const float* __restrict__ value,
    const float* __restrict__ W, const float* __restrict__ b,
    unsigned short* __restrict__ projB, unsigned short* __restrict__ mpvB)
{
  __shared__ __align__(16) float pkK[64 * 68];
  __shared__ __align__(16) float pkV[68 * 68];
  __shared__ float coefs[64 * 4];
  const int t = threadIdx.x;
  const int bid = blockIdx.x;
  const int bh = bid / 30;
  const int tt = bid % 30;
  if (tt < 16)
    prep_body<0>(key, value, W, b, projB, mpvB, bh, tt, t, pkK, pkV, coefs);
  else if (tt < 24)
    prep_body<1>(key, value, W, b, projB, mpvB, bh, tt - 16, t, pkK, pkV, coefs);
  else if (tt < 28)
    prep_body<2>(key, value, W, b, projB, mpvB, bh, tt - 24, t, pkK, pkV, coefs);
  else
    prep_body<3>(key, value, W, b, projB, mpvB, bh, tt - 28, t, pkK, pkV, coefs);
}

// ---------------------------------------------------------------------------
// FUSED: R7 structure (117us verified) + two VALU-targeted epilogue changes:
//  (d) P2 drops the normalize pass; unnormalized exp stays in LDS, 1/sum ->
//      sInv[16][4] (256B LDS).  One fewer bf16 rounding of P.
//  (e) P3 segments the accumulator per scale (s0..s3, +12 VGPR, more MFMA
//      ILP) and folds sInv in the epilogue.  P4 loop-interchanged: thread
//      owns fixed columns k0=t*4, interp coefficients hoisted out of the
//      16-row loop (~1500 -> ~100 VALU insts/thread of index math).
// ---------------------------------------------------------------------------
__global__ __launch_bounds__(256, 2) void fused_attn_kernel(
    const float* __restrict__ query, const unsigned short* __restrict__ projB,
    const unsigned short* __restrict__ mpvB, float* __restrict__ out)
{
  __shared__ __align__(16) unsigned short prbf[16 * PSTR];
  __shared__ float sInv[16 * 4];
  const int t    = threadIdx.x;
  // XCD-aware bh-colocating swizzle (bijective: 2048 = 8 xcd * 4 bh * 64 qt)
  const int bid  = blockIdx.x;
  const int xcd  = bid & 7;
  const int slot = bid >> 3;              // 0..255 within this XCD's share
  const int bh   = xcd * 4 + (slot >> 6); // 4 consecutive heads per XCD
  const int qt   = slot & 63;
  const int q0   = qt << 4;
  const int wave = t >> 6;
  const int lane = t & 63;
  const int quad = lane >> 4;
  const int n16  = lane & 15;

  // A-frags: A[m=lane&15][k=quad*8+j], k = d (+32 for second frag)
  bf8_t af0, af1;
  {
    const float* qrow = query + bh * (S_LEN * DH) + (q0 + n16) * DH;
    const float4 a0 = *(const float4*)(qrow + quad * 8);
    const float4 a1 = *(const float4*)(qrow + quad * 8 + 4);
    const float4 a2 = *(const float4*)(qrow + 32 + quad * 8);
    const float4 a3 = *(const float4*)(qrow + 32 + quad * 8 + 4);
    af0[0] = (short)f2bf(a0.x); af0[1] = (short)f2bf(a0.y);
    af0[2] = (short)f2bf(a0.z); af0[3] = (short)f2bf(a0.w);
    af0[4] = (short)f2bf(a1.x); af0[5] = (short)f2bf(a1.y);
    af0[6] = (short)f2bf(a1.z); af0[7] = (short)f2bf(a1.w);
    af1[0] = (short)f2bf(a2.x); af1[1] = (short)f2bf(a2.y);
    af1[2] = (short)f2bf(a2.z); af1[3] = (short)f2bf(a2.w);
    af1[4] = (short)f2bf(a3.x); af1[5] = (short)f2bf(a3.y);
    af1[6] = (short)f2bf(a3.z); af1[7] = (short)f2bf(a3.w);
  }

  // ---- P1: scores via MFMA; write bf16 to LDS (depth-2 global prefetch) ----
  {
    const bf8_t* pB = (const bf8_t*)projB + bh * NCHUNK;
    bf8_t pb0 = pB[(wave * 2 + 0) * 64 + lane];
    bf8_t pb1 = pB[(wave * 2 + 1) * 64 + lane];
    for (int kt = wave; kt < 120; kt += 4) {
      const int ktn = min(kt + 4, 119);       // tail prefetch clamped (re-read)
      const bf8_t nb0 = pB[(ktn * 2 + 0) * 64 + lane];
      const bf8_t nb1 = pB[(ktn * 2 + 1) * 64 + lane];
      f32x4_t c = {0.f, 0.f, 0.f, 0.f};
      c = __builtin_amdgcn_mfma_f32_16x16x32_bf16(af0, pb0, c, 0, 0, 0);
      c = __builtin_amdgcn_mfma_f32_16x16x32_bf16(af1, pb1, c, 0, 0, 0);
      const int col = kt * 16 + n16;
      #pragma unroll
      for (int i = 0; i < 4; i++)
        prbf[(quad * 4 + i) * PSTR + col] = f2bf(c[i] * 0.125f);
      pb0 = nb0; pb1 = nb1;
    }
  }
  __syncthreads();

  // ---- P2: per-row per-scale max + exp (UNNORMALIZED); 1/sum -> sInv ----
  {
    const int rr = t >> 4;
    const int g  = t & 15;
    unsigned short* prr = prbf + rr * PSTR;
    #pragma unroll
    for (int si = 0; si < 4; si++) {
      const int L   = 1024 >> si;
      const int off = (si == 0) ? 0 : (si == 1) ? 1024 : (si == 2) ? 1536 : 1792;
      const int nch = L >> 2;
      float m = -1e30f;
      for (int ch = g; ch < nch; ch += 16) {
        const ushort4 u = *(const ushort4*)(prr + off + ch * 4);
        m = fmaxf(m, fmaxf(fmaxf(bf2f(u.x), bf2f(u.y)),
                           fmaxf(bf2f(u.z), bf2f(u.w))));
      }
      #pragma unroll
      for (int dlt = 8; dlt >= 1; dlt >>= 1) m = fmaxf(m, __shfl_xor(m, dlt));
      float ssum = 0.f;
      for (int ch = g; ch < nch; ch += 16) {
        ushort4 u = *(const ushort4*)(prr + off + ch * 4);
        const float e0 = __expf(bf2f(u.x) - m);
        const float e1 = __expf(bf2f(u.y) - m);
        const float e2 = __expf(bf2f(u.z) - m);
        const float e3 = __expf(bf2f(u.w) - m);
        ssum += (e0 + e1) + (e2 + e3);
        u.x = f2bf(e0); u.y = f2bf(e1); u.z = f2bf(e2); u.w = f2bf(e3);
        *(ushort4*)(prr + off + ch * 4) = u;
      }
      #pragma unroll
      for (int dlt = 8; dlt >= 1; dlt >>= 1) ssum += __shfl_xor(ssum, dlt);
      if (g == 0) sInv[rr * 4 + si] = 1.0f / ssum;
    }
  }
  __syncthreads();

  // ---- P3: per-scale segmented MFMA, sInv folded in epilogue ----
  {
    const bf8_t* pM = (const bf8_t*)mpvB + bh * NCHUNK;
    f32x4_t s0 = {0.f, 0.f, 0.f, 0.f}, s1 = s0, s2 = s0, s3 = s0;
    bf8_t bb0 = pM[(0 * 4 + wave) * 64 + lane];
    bf8_t bb1 = pM[(1 * 4 + wave) * 64 + lane];
    #define P3_STEP(ACC, KB)                                                   \
      {                                                                        \
        const int kbn = min((KB) + 2, 59);                                     \
        const bf8_t bbn = pM[(kbn * 4 + wave) * 64 + lane];                    \
        const bf8_t a =                                                        \
            *(const bf8_t*)(prbf + n16 * PSTR + (KB) * 32 + quad * 8);         \
        ACC = __builtin_amdgcn_mfma_f32_16x16x32_bf16(a, bb0, ACC, 0, 0, 0);   \
        bb0 = bb1; bb1 = bbn;                                                  \
      }
    for (int kb = 0; kb < 32; kb++)  P3_STEP(s0, kb)
    for (int kb = 32; kb < 48; kb++) P3_STEP(s1, kb)
    for (int kb = 48; kb < 56; kb++) P3_STEP(s2, kb)
    for (int kb = 56; kb < 60; kb++) P3_STEP(s3, kb)
    #undef P3_STEP
    float* ob = out + bh * (S_LEN * DH) + q0 * DH;
    #pragma unroll
    for (int i = 0; i < 4; i++) {
      const int row = quad * 4 + i;
      const float val =
          0.25f * (s0[i] * sInv[row * 4 + 0] + s1[i] * sInv[row * 4 + 1] +
                   s2[i] * sInv[row * 4 + 2] + s3[i] * sInv[row * 4 + 3]);
      __builtin_nontemporal_store(val, &ob[row * DH + wave * 16 + n16]);
    }
  }

  // ---- P4: combined_attention; fixed columns/thread, hoisted coefs ----
  {
    float* ab = out + ATTN_OFF + (size_t)bh * (S_LEN * S_LEN) + (size_t)q0 * S_LEN;
    const int k0 = t << 2;     // thread owns columns k0..k0+3 for all 16 rows
    int   io0[3][4], io1[3][4];
    float wgt[3][4];
    #pragma unroll
    for (int si = 1; si < 4; si++) {
      const int   L     = 1024 >> si;
      const int   off2  = (si == 1) ? 1024 : (si == 2) ? 1536 : 1792;
      const float inv_s = (si == 1) ? 0.5f : (si == 2) ? 0.25f : 0.125f;
      #pragma unroll
      for (int kk = 0; kk < 4; kk++) {
        float srcp = ((float)(k0 + kk) + 0.5f) * inv_s - 0.5f;
        srcp = fminf(fmaxf(srcp, 0.f), (float)(L - 1));
        const int i0 = (int)floorf(srcp);
        io0[si - 1][kk] = off2 + i0;
        io1[si - 1][kk] = off2 + min(i0 + 1, L - 1);
        wgt[si - 1][kk] = srcp - (float)i0;
      }
    }
    for (int rr = 0; rr < 16; rr++) {
      const unsigned short* p2 = prbf + rr * PSTR;
      const float iv0 = sInv[rr * 4 + 0];
      const float iv1 = sInv[rr * 4 + 1];
      const float iv2 = sInv[rr * 4 + 2];
      const float iv3 = sInv[rr * 4 + 3];
      const ushort4 bs = *(const ushort4*)(p2 + k0);
      float res[4] = {bf2f(bs.x) * iv0, bf2f(bs.y) * iv0,
                      bf2f(bs.z) * iv0, bf2f(bs.w) * iv0};
      #pragma unroll
      for (int si = 1; si < 4; si++) {
        const float ivs = (si == 1) ? iv1 : (si == 2) ? iv2 : iv3;
        #pragma unroll
        for (int kk = 0; kk < 4; kk++) {
          const float w  = wgt[si - 1][kk];
          const float e0 = bf2f(p2[io0[si - 1][kk]]);
          const float e1 = bf2f(p2[io1[si - 1][kk]]);
          res[kk] += ivs * (e0 + w * (e1 - e0));
        }
      }
      f32x4_t o4;
      o4[0] = res[0] * 0.25f; o4[1] = res[1] * 0.25f;
      o4[2] = res[2] * 0.25f; o4[3] = res[3] * 0.25f;
      __builtin_nontemporal_store(o4, (f32x4_t*)(ab + rr * 1024 + k0));
    }
  }
}

// ---------------------------------------------------------------------------
extern "C" void kernel_launch(void* const* d_in, const int* in_sizes, int n_in,
                              void* d_out, int out_size, void* d_ws, size_t ws_size,
                              hipStream_t stream) {
  (void)in_sizes; (void)n_in; (void)out_size; (void)ws_size;
  const float* query = (const float*)d_in[0];
  const float* key   = (const float*)d_in[1];
  const float* value = (const float*)d_in[2];
  const float* W     = (const float*)d_in[3];
  const float* b     = (const float*)d_in[4];
  float* out = (float*)d_out;

  unsigned short* projB = (unsigned short*)d_ws;                 // 7.9 MB bf16
  unsigned short* mpvB  = projB + (size_t)NBH * HEAD_K;          // 7.9 MB bf16

  prep_kernel<<<NBH * 30, 256, 0, stream>>>(key, value, W, b, projB, mpvB);
  fused_attn_kernel<<<NBH * 64, 256, 0, stream>>>(query, projB, mpvB, out);
}